// Round 1
// baseline (110.931 us; speedup 1.0000x reference)
//
#include <hip/hip_runtime.h>

// Network24: out = sigmoid( m0*h0 + m1*h1 + (m2*h0)*(m3*h1) + bias3 )
//   h_j = sigmoid( tw[j][0]*x0^p[j][0] + tw[j][1]*x1^p[j][1] + b_j )
// Powers are 1.0 at runtime; uniform branch keeps the general case correct.

__device__ __forceinline__ float pw(float x, float p) {
    return (p == 1.0f) ? x : __powf(x, p);
}
__device__ __forceinline__ float sigmoidf(float z) {
    return 1.0f / (1.0f + __expf(-z));
}

__global__ __launch_bounds__(256) void net24_kernel(
    const float* __restrict__ x,        // (n, 2) row-major
    float* __restrict__ out,            // (n,)
    const float* __restrict__ fc1_tw,   // (2,2,3) -> use [j,k,0] = j*6+k*3
    const float* __restrict__ fc1_power,// (2,2)
    const float* __restrict__ fc1_bias, // (2,)
    const float* __restrict__ m4_tw,    // (4,3) -> use [i,0] = i*3
    const float* __restrict__ m4_power, // (4,)
    const float* __restrict__ m4_bias3, // (1,)
    int n)                              // rows
{
    // Uniform addresses -> scalar loads, broadcast to all lanes.
    const float tw00 = fc1_tw[0], tw01 = fc1_tw[3], tw10 = fc1_tw[6], tw11 = fc1_tw[9];
    const float p00 = fc1_power[0], p01 = fc1_power[1], p10 = fc1_power[2], p11 = fc1_power[3];
    const float b0 = fc1_bias[0], b1 = fc1_bias[1];
    const float m0 = m4_tw[0], m1 = m4_tw[3], m2 = m4_tw[6], m3 = m4_tw[9];
    const float q0 = m4_power[0], q1 = m4_power[1], q2 = m4_power[2], q3 = m4_power[3];
    const float bias3 = m4_bias3[0];

    const int i = blockIdx.x * blockDim.x + threadIdx.x;  // group of 4 rows
    const int row0 = i * 4;
    if (row0 >= n) return;

    auto eval_row = [&](float x0, float x1) -> float {
        float h0 = sigmoidf(fmaf(tw00, pw(x0, p00), fmaf(tw01, pw(x1, p01), b0)));
        float h1 = sigmoidf(fmaf(tw10, pw(x0, p10), fmaf(tw11, pw(x1, p11), b1)));
        float s  = fmaf(m0, pw(h0, q0), fmaf(m1, pw(h1, q1), bias3));
        s = fmaf(m2 * pw(h0, q2), m3 * pw(h1, q3), s);
        return sigmoidf(s);
    };

    if (row0 + 4 <= n) {
        // Vector path: 2x float4 load (8 floats = 4 rows), 1x float4 store.
        const float4* xv = (const float4*)(x + (size_t)row0 * 2);
        float4 a = xv[0];
        float4 b = xv[1];
        float4 r;
        r.x = eval_row(a.x, a.y);
        r.y = eval_row(a.z, a.w);
        r.z = eval_row(b.x, b.y);
        r.w = eval_row(b.z, b.w);
        *(float4*)(out + row0) = r;
    } else {
        for (int r = row0; r < n; ++r) {
            out[r] = eval_row(x[(size_t)r * 2], x[(size_t)r * 2 + 1]);
        }
    }
}

extern "C" void kernel_launch(void* const* d_in, const int* in_sizes, int n_in,
                              void* d_out, int out_size, void* d_ws, size_t ws_size,
                              hipStream_t stream) {
    const float* x         = (const float*)d_in[0];
    const float* fc1_tw    = (const float*)d_in[1];
    const float* fc1_power = (const float*)d_in[2];
    const float* fc1_bias  = (const float*)d_in[3];
    const float* m4_tw     = (const float*)d_in[4];
    const float* m4_power  = (const float*)d_in[5];
    const float* m4_bias3  = (const float*)d_in[6];
    float* out = (float*)d_out;

    const int n = out_size;               // B rows, one output each
    const int n4 = (n + 3) / 4;           // rows handled 4-per-thread
    const int block = 256;
    const int grid = (n4 + block - 1) / block;

    net24_kernel<<<grid, block, 0, stream>>>(x, out, fc1_tw, fc1_power, fc1_bias,
                                             m4_tw, m4_power, m4_bias3, n);
}